// Round 9
// baseline (1675.071 us; speedup 1.0000x reference)
//
#include <hip/hip_runtime.h>
#include <cstdint>

// ---------------------------------------------------------------------------
// Gemma4 audio local attention, MI355X/gfx950.
// Pipeline: x->bf16 | W^T(+scales)->bf16 | sinusoid emb | QKV GEMM (256x256,
// BK=32, 64KB LDS -> 2 blocks/CU co-residency) | pos GEMM (split-K x3) |
// fused local attention (8 waves, LDS-staged K/V).
// ---------------------------------------------------------------------------

typedef __attribute__((ext_vector_type(8))) short s16x8;   // 8 x bf16 (4 VGPR)
typedef __attribute__((ext_vector_type(4))) float f32x4;
typedef __attribute__((ext_vector_type(4))) unsigned short u16x4;

#define MFMA16(A, B, C) __builtin_amdgcn_mfma_f32_16x16x32_bf16(A, B, C, 0, 0, 0)

__device__ __forceinline__ unsigned short f2bf(float f) {
  unsigned u = __float_as_uint(f);
  u += 0x7FFFu + ((u >> 16) & 1u);          // RNE
  return (unsigned short)(u >> 16);
}
__device__ __forceinline__ float bf2f(unsigned short s) {
  return __uint_as_float(((unsigned)s) << 16);
}

// async global->LDS, 16B per lane. LDS dest is wave-uniform base + lane*16
// (linear in tid); global source is per-lane (pre-swizzled there).
__device__ __forceinline__ void gload16(const unsigned short* g, unsigned short* l) {
  __builtin_amdgcn_global_load_lds(
      (const __attribute__((address_space(1))) void*)(uintptr_t)g,
      (__attribute__((address_space(3))) void*)(unsigned)(uintptr_t)l,
      16, 0, 0);
}

// ---------------------------------------------------------------------------
// x f32 [16384][1536] -> bf16
__global__ void convert_x(const float4* __restrict__ x4, u16x4* __restrict__ o4) {
  int idx = blockIdx.x * 256 + threadIdx.x;
  #pragma unroll
  for (int i = 0; i < 12; ++i) {
    size_t k = (size_t)idx + (size_t)i * 524288;
    float4 v = x4[k];
    u16x4 o = {f2bf(v.x), f2bf(v.y), f2bf(v.z), f2bf(v.w)};
    o4[k] = o;
  }
}

// ---------------------------------------------------------------------------
// W^T with per-output-dim scales, bf16. Wt rows: [0,1536)=Wq^T*qscale,
// [1536,3072)=Wk^T*K_SCALE, [3072,4608)=Wv^T, [4608,6144)=Wpos^T.
__global__ void wt_kernel(const float* __restrict__ Wq, const float* __restrict__ Wk,
                          const float* __restrict__ Wv, const float* __restrict__ Wpos,
                          const float* __restrict__ pds, unsigned short* __restrict__ Wt) {
  int z = blockIdx.z;
  const float* W = (z == 0) ? Wq : (z == 1) ? Wk : (z == 2) ? Wv : Wpos;
  int k0 = blockIdx.x * 64, n0 = blockIdx.y * 64;
  __shared__ float tile[64][65];
  int tid = threadIdx.x;
  #pragma unroll
  for (int i = 0; i < 16; ++i) {
    int lin = i * 256 + tid, r = lin >> 6, c = lin & 63;
    tile[r][c] = W[(size_t)(k0 + r) * 1536 + n0 + c];
  }
  __syncthreads();
  const float LN2 = 0.6931471805599453f;
  #pragma unroll
  for (int i = 0; i < 16; ++i) {
    int lin = i * 256 + tid, r = lin >> 6, c = lin & 63;
    int nn = n0 + r;
    float scale = 1.f;
    if (z == 0) {
      float p = pds[nn & 127];
      float sp = (p > 20.f) ? p : log1pf(expf(p));
      scale = (0.08838834764831845f / LN2) * sp;   // Dh^-0.5/ln2 * softplus
    } else if (z == 1) {
      scale = 1.3132616875182228f / LN2;           // log1p(e)/ln2
    }
    Wt[(size_t)(z * 1536 + nn) * 1536 + k0 + c] = f2bf(tile[c][r] * scale);
  }
}

// ---------------------------------------------------------------------------
// sinusoidal embedding rows: emb[p][i], position = 127-p
__global__ void emb_kernel(unsigned short* __restrict__ emb) {
  int p = blockIdx.x, tid = threadIdx.x;
  float position = (float)(127 - p);
  float log_inc = logf(10000.f) / 767.f;
  #pragma unroll
  for (int j = 0; j < 6; ++j) {
    int i = tid + j * 256;
    int ii = (i < 768) ? i : i - 768;
    float arg = position * expf(-(float)ii * log_inc);
    float v = (i < 768) ? sinf(arg) : cosf(arg);
    emb[(size_t)p * 1536 + i] = f2bf(v);
  }
}

// ---------------------------------------------------------------------------
// 256x256x(K=1536) bf16 GEMM, BK=32, 64KB LDS double-buffer -> 2 blocks/CU.
// Simple loop: stage(next) | 12x swizzled ds_read_b128 | 32 MFMA | barrier.
// Co-resident block fills barrier/vmcnt stalls (m97/m114 mechanism).
// Tile LDS layout: 256x32 bf16 as 16 subtiles of 16x32 (1KB); within subtile
// byte ^= ((byte>>9)&1)<<5 (st_16x32). Conflict-free (measured 0, R2-R8).
// Y = X@[Wq|Wk|Wv]^T -> q[b][h][t][d], k[b][h][127+t][d], v^T[b][h][d][127+t]
__global__ __launch_bounds__(512, 4) void gemm256b_kernel(
    const unsigned short* __restrict__ A, const unsigned short* __restrict__ Bw,
    unsigned short* __restrict__ outq, unsigned short* __restrict__ outk,
    unsigned short* __restrict__ outv) {
  __shared__ __align__(16) unsigned short lds[32768];  // 64KB: 2 x (A 16K + B 16K bytes)
  const int tid = threadIdx.x;
  const int w = tid >> 6, l = tid & 63, g = l >> 4, li = l & 15;
  const int wm = w >> 2, wn = w & 3;

  // XCD-bijective swizzle (1152 % 8 == 0) + 8x6 supertiles for L2 locality
  int swz = (blockIdx.x & 7) * 144 + (blockIdx.x >> 3);
  int grp = swz / 48, idx = swz % 48;
  const int tm = (grp / 3) * 8 + idx / 6;    // 0..63
  const int tn = (grp % 3) * 6 + idx % 6;    // 0..17

  const unsigned short* Ab = A + (size_t)tm * 256 * 1536;
  const unsigned short* Bb = Bw + (size_t)tn * 256 * 1536;

  // per-thread inverse-swizzle source coords for chunks {tid, 512+tid} of a
  // 256x32 tile (1024 x 16B chunks; subtile = 16 rows, chunk q -> sub=q>>6)
  int sr0, sc0, sr1, sc1;
  {
    int q = tid, off = (q & 63) << 4;
    off ^= ((off >> 9) & 1) << 5;
    sr0 = (q >> 6) * 16 + (off >> 6);
    sc0 = (off & 63) >> 1;
    q = 512 + tid; off = (q & 63) << 4;
    off ^= ((off >> 9) & 1) << 5;
    sr1 = (q >> 6) * 16 + (off >> 6);
    sc1 = (off & 63) >> 1;
  }
  auto stage = [&](int buf, int kt) {
    int k0 = kt * 32;
    if (k0 >= 1536) k0 = 0;                  // tail prefetch: dead data, valid mem
    unsigned short* d = (unsigned short*)lds + buf * 16384;
    gload16(Ab + (size_t)sr0 * 1536 + k0 + sc0, d + tid * 8);
    gload16(Ab + (size_t)sr1 * 1536 + k0 + sc1, d + 4096 + tid * 8);
    gload16(Bb + (size_t)sr0 * 1536 + k0 + sc0, d + 8192 + tid * 8);
    gload16(Bb + (size_t)sr1 * 1536 + k0 + sc1, d + 12288 + tid * 8);
  };
  // swizzled frag read from a 256x32 tile (row mult of 16 + li, col = g*8)
  auto frag = [&](const unsigned short* tile, int row, int col) -> s16x8 {
    int byte = ((row >> 4) << 10) +
               (((((row & 15) << 6) | ((col & 31) << 1))) ^ ((row & 8) << 2));
    return *(const s16x8*)((const char*)tile + byte);
  };

  f32x4 acc[8][4];
  #pragma unroll
  for (int i = 0; i < 8; ++i)
    #pragma unroll
    for (int j = 0; j < 4; ++j) acc[i][j] = f32x4{0.f, 0.f, 0.f, 0.f};

  stage(0, 0);
  __syncthreads();
  for (int t = 0; t < 48; ++t) {
    if (t < 47) stage((t + 1) & 1, t + 1);   // issue next-tile loads FIRST
    const unsigned short* At = lds + (t & 1) * 16384;
    const unsigned short* Bt = At + 8192;
    s16x8 af[8], bf[4];
    #pragma unroll
    for (int mi = 0; mi < 8; ++mi)
      af[mi] = frag(At, wm * 128 + mi * 16 + li, g * 8);
    #pragma unroll
    for (int ni = 0; ni < 4; ++ni)
      bf[ni] = frag(Bt, wn * 64 + ni * 16 + li, g * 8);
    #pragma unroll
    for (int mi = 0; mi < 8; ++mi)
      #pragma unroll
      for (int ni = 0; ni < 4; ++ni)
        acc[mi][ni] = MFMA16(af[mi], bf[ni], acc[mi][ni]);
    __syncthreads();                          // compiler drains vmcnt/lgkm here
  }

  // epilogue scatter: C/D layout col=lane&15, row=(lane>>4)*4+reg
  #pragma unroll
  for (int mf = 0; mf < 8; ++mf) {
    int mrow = tm * 256 + wm * 128 + mf * 16 + g * 4;
    int bb_ = mrow >> 12, tt = mrow & 4095;
    #pragma unroll
    for (int fj = 0; fj < 4; ++fj) {
      int ncol = tn * 256 + wn * 64 + fj * 16 + li;
      f32x4 v4 = acc[mf][fj];
      if (ncol < 1536) {
        int hh = ncol >> 7, dd = ncol & 127;
        #pragma unroll
        for (int r = 0; r < 4; ++r)
          outq[((size_t)(bb_ * 12 + hh) * 4096 + tt + r) * 128 + dd] = f2bf(v4[r]);
      } else if (ncol < 3072) {
        int nc = ncol - 1536, hh = nc >> 7, dd = nc & 127;
        #pragma unroll
        for (int r = 0; r < 4; ++r)
          outk[((size_t)(bb_ * 12 + hh) * 4224 + 127 + tt + r) * 128 + dd] = f2bf(v4[r]);
      } else {
        int nc = ncol - 3072, hh = nc >> 7, dd = nc & 127;
        size_t vo = ((size_t)(bb_ * 12 + hh) * 128 + dd) * 4352 + 127 + tt;
        #pragma unroll
        for (int r = 0; r < 4; ++r) outv[vo + r] = f2bf(v4[r]);
      }
    }
  }
}

// ---------------------------------------------------------------------------
// pos GEMM split-K: 128x(128x12)x512 per slice, 3 slices -> f32 partials.
// part[ks][p][col] f32; grid 36 = 12 tn x 3 ks.
__global__ __launch_bounds__(256, 2) void posgemm_kernel(
    const unsigned short* __restrict__ A, const unsigned short* __restrict__ Bw,
    float* __restrict__ part) {
  __shared__ __align__(16) unsigned short smem[2][16384];
  const int tid = threadIdx.x;
  const int w = tid >> 6, l = tid & 63, g = l >> 4, li = l & 15;
  const int wr = w >> 1, wc = w & 1;
  const int tn = blockIdx.x % 12, ks = blockIdx.x / 12;

  const unsigned short* Ab = A;
  const unsigned short* Bb = Bw + (size_t)tn * 128 * 1536;

  f32x4 acc[4][4];
  #pragma unroll
  for (int i = 0; i < 4; ++i)
    #pragma unroll
    for (int j = 0; j < 4; ++j) acc[i][j] = f32x4{0.f, 0.f, 0.f, 0.f};

  auto stage = [&](int buf, int kk) {
    unsigned short* s = smem[buf];
    #pragma unroll
    for (int it = 0; it < 4; ++it) {
      int chunk = it * 256 + tid;
      int r = chunk >> 3, cs = chunk & 7;
      gload16(Ab + (size_t)r * 1536 + kk * 64 + ((cs ^ (r & 7)) << 3), s + chunk * 8);
    }
    #pragma unroll
    for (int it = 0; it < 4; ++it) {
      int chunk = it * 256 + tid;
      int r = chunk >> 3, cs = chunk & 7;
      gload16(Bb + (size_t)r * 1536 + kk * 64 + ((cs ^ (r & 7)) << 3),
              s + 8192 + chunk * 8);
    }
  };

  stage(0, ks * 8);
  __syncthreads();
  for (int t = 0; t < 8; ++t) {
    if (t < 7) stage((t + 1) & 1, ks * 8 + t + 1);
    const unsigned short* s = smem[t & 1];
    #pragma unroll
    for (int kk = 0; kk < 2; ++kk) {
      s16x8 af[4], bfm[4];
      #pragma unroll
      for (int mi = 0; mi < 4; ++mi) {
        int ar = wr * 64 + mi * 16 + li;
        int ch = (kk * 4 + g) ^ (ar & 7);
        af[mi] = *(const s16x8*)(s + ar * 64 + ch * 8);
      }
      #pragma unroll
      for (int ni = 0; ni < 4; ++ni) {
        int br = wc * 64 + ni * 16 + li;
        int ch = (kk * 4 + g) ^ (br & 7);
        bfm[ni] = *(const s16x8*)(s + 8192 + br * 64 + ch * 8);
      }
      #pragma unroll
      for (int mi = 0; mi < 4; ++mi)
        #pragma unroll
        for (int ni = 0; ni < 4; ++ni)
          acc[mi][ni] = MFMA16(af[mi], bfm[ni], acc[mi][ni]);
    }
    __syncthreads();
  }

  #pragma unroll
  for (int mi = 0; mi < 4; ++mi) {
    int mrow = wr * 64 + mi * 16 + g * 4;
    #pragma unroll
    for (int ni = 0; ni < 4; ++ni) {
      int ncol = tn * 128 + wc * 64 + ni * 16 + li;
      f32x4 v4 = acc[mi][ni];
      #pragma unroll
      for (int r = 0; r < 4; ++r)
        part[((size_t)ks * 128 + mrow + r) * 1536 + ncol] = v4[r];
    }
  }
}

// reduce 3 f32 partials -> posb[h][p][d] bf16
__global__ void posreduce_kernel(const float* __restrict__ part,
                                 unsigned short* __restrict__ posb) {
  int e = (blockIdx.x * 256 + threadIdx.x) * 4;   // 196608 elems, grid 192
  float4 a = *(const float4*)(part + e);
  float4 b = *(const float4*)(part + 196608 + e);
  float4 c = *(const float4*)(part + 393216 + e);
  int p = e / 1536, col = e % 1536;
  u16x4 o = {f2bf(a.x + b.x + c.x), f2bf(a.y + b.y + c.y),
             f2bf(a.z + b.z + c.z), f2bf(a.w + b.w + c.w)};
  *(u16x4*)(posb + ((size_t)(col >> 7) * 128 + p) * 128 + (col & 127)) = o;
}

// ---------------------------------------------------------------------------
// Fused blocked local attention (R4 version, proven). 1 block = (b,h,n)
// 128-query tile, 8 waves x 16 q-rows. K/V staged cooperatively into a 32KB
// LDS buffer (time-shared K0,K1,V0,V1) via global_load_lds with XOR-swizzled
// source; QP then P live in a second 32KB region (wave-private rows).
__global__ __launch_bounds__(512, 4) void attn_kernel(
    const unsigned short* __restrict__ qb, const unsigned short* __restrict__ kb,
    const unsigned short* __restrict__ vt, const unsigned short* __restrict__ posb,
    float* __restrict__ out) {
  __shared__ __align__(16) unsigned short kv[16384];    // 32KB: K/V half-tiles
  __shared__ __align__(16) unsigned short pbuf[16384];  // 32KB: QP then P
  const int tid = threadIdx.x;
  const int w = tid >> 6, l = tid & 63, g = l >> 4, li = l & 15;
  int bid = blockIdx.x;
  bid = (bid & 7) * 192 + (bid >> 3);   // XCD swizzle: adjacent n share K/V
  const int n = bid & 31, h = (bid >> 5) % 12, b = bid / 384;
  const int qrow0 = w * 16;             // wave-local q base (block-local)

  auto stageK = [&](int half) {
    const unsigned short* kb0 =
        kb + ((size_t)(b * 12 + h) * 4224 + n * 128 + half * 128) * 128;
    #pragma unroll
    for (int it = 0; it < 4; ++it) {
      int chunk = it * 512 + tid;
      int row = chunk >> 4, sl = chunk & 15;
      gload16(kb0 + row * 128 + ((sl ^ ((row & 7) << 1)) << 3), kv + chunk * 8);
    }
  };
  auto stageV = [&](int half) {
    const unsigned short* vb0 =
        vt + (size_t)(b * 12 + h) * 128 * 4352 + n * 128 + half * 128;
    #pragma unroll
    for (int it = 0; it < 4; ++it) {
      int chunk = it * 512 + tid;
      int row = chunk >> 4, sl = chunk & 15;
      gload16(vb0 + (size_t)row * 4352 + ((sl ^ ((row & 7) << 1)) << 3),
              kv + chunk * 8);
    }
  };

  stageK(0);  // issue ASAP; QP compute below overlaps the loads

  // ---- Q fragments (A-frag: row=li, k = kt*32+g*8)
  s16x8 aq[4];
  const unsigned short* qbase =
      qb + ((size_t)(b * 12 + h) * 4096 + n * 128 + qrow0 + li) * 128 + g * 8;
  #pragma unroll
  for (int kt = 0; kt < 4; ++kt) aq[kt] = *(const s16x8*)(qbase + kt * 32);

  // ---- QP = Q * pos^T -> pbuf rows [qrow0, qrow0+16), linear [q][p]
  const unsigned short* pb = posb + (size_t)h * 128 * 128;
  #pragma unroll
  for (int pt = 0; pt < 8; ++pt) {
    f32x4 a = {0.f, 0.f, 0.f, 0.f};
    #pragma unroll
    for (int kt = 0; kt < 4; ++kt) {
      s16x8 bp = *(const s16x8*)(pb + (pt * 16 + li) * 128 + kt * 32 + g * 8);
      a = MFMA16(aq[kt], bp, a);
    }
    #pragma unroll
    for (int r = 0; r < 4; ++r)
      pbuf[(qrow0 + g * 4 + r) * 128 + pt * 16 + li] = f2bf(a[r]);
  }

  f32x4 S[16];

  auto sHalf = [&](int half) {
    #pragma unroll
    for (int c8 = 0; c8 < 8; ++c8) {
      int rowc = c8 * 16 + li;
      f32x4 s = {0.f, 0.f, 0.f, 0.f};
      #pragma unroll
      for (int kt = 0; kt < 4; ++kt) {
        int slot = (kt * 4 + g) ^ ((rowc & 7) << 1);
        s16x8 bk = *(const s16x8*)(kv + rowc * 128 + slot * 8);
        s = MFMA16(aq[kt], bk, s);
      }
      S[half * 8 + c8] = s;
    }
    #pragma unroll
    for (int c8 = 0; c8 < 8; ++c8) {
      int ct = half * 8 + c8;
      #pragma unroll
      for (int r = 0; r < 4; ++r) {
        int qq = qrow0 + g * 4 + r;       // block-local q
        int cc = ct * 16 + li;            // block-local ctx
        int p = cc - qq;
        bool win = ((unsigned)p < 128u);
        float bd = bf2f(pbuf[qq * 128 + (p & 127)]);
        float sv = S[ct][r] + (win ? bd : 0.f);
        float e2 = exp2f(sv * 0.0577078016355585f);   // (2/50)*log2(e)
        sv = 50.f - 100.f / (e2 + 1.f);               // 50*tanh(s/50), NaN-free
        bool vld = win && (n * 128 + cc >= 127);      // key t >= 0
        S[ct][r] = vld ? sv : -3e38f;
      }
    }
  };

  __syncthreads();          // K0 resident
  sHalf(0);
  __syncthreads();          // all waves done reading K0
  stageK(1);
  __syncthreads();          // K1 resident
  sHalf(1);

  // ---- softmax (full row in regs)
  float inv_[4];
  #pragma unroll
  for (int r = 0; r < 4; ++r) {
    float m_ = -3e38f;
    #pragma unroll
    for (int ct = 0; ct < 16; ++ct) m_ = fmaxf(m_, S[ct][r]);
    #pragma unroll
    for (int d = 1; d < 16; d <<= 1) m_ = fmaxf(m_, __shfl_xor(m_, d));
    float sum = 0.f;
    #pragma unroll
    for (int ct = 0; ct < 16; ++ct) {
      float e = exp2f((S[ct][r] - m_) * 1.4426950408889634f);
      S[ct][r] = e;
      sum += e;
    }
    #pragma unroll
    for (int d = 1; d < 16; d <<= 1) sum += __shfl_xor(sum, d);
    inv_[r] = 1.f / sum;
  }

  f32x4 O[8];
  #pragma unroll
  for (int jt = 0; jt < 8; ++jt) O[jt] = f32x4{0.f, 0.f, 0.f, 0.f};
  s16x8 pa[4];

  auto writeP = [&](int half) {
    #pragma unroll
    for (int c8 = 0; c8 < 8; ++c8)
      #pragma unroll
      for (int r = 0; r < 4; ++r) {
        int row = qrow0 + g * 4 + r;
        int slot = (c8 * 2 + (li >> 3)) ^ ((row & 7) << 1);
        pbuf[row * 128 + slot * 8 + (li & 7)] = f2bf(S[half * 8 + c8][r] * inv_[r]);
      }
  };
  auto readPA = [&]() {
    #pragma unroll
    for (int c = 0; c < 4; ++c) {
      int row = qrow0 + li;
      int slot = (c * 4 + g) ^ ((li & 7) << 1);
      pa[c] = *(const s16x8*)(pbuf + row * 128 + slot * 8);
    }
  };
  auto pvHalf = [&]() {
    #pragma unroll
    for (int jt = 0; jt < 8; ++jt) {
      int rowd = jt * 16 + li;
      #pragma unroll
      for (int c = 0; c < 4; ++c) {
        int slot = (c * 4 + g) ^ ((rowd & 7) << 1);
        s16x8 bv = *(const s16x8*)(kv + rowd * 128 + slot * 8);
        O[jt] = MFMA16(pa[c], bv, O[jt]);
      }
    }
  };

  __syncthreads();          // all waves done reading K1 (kv free for V0)
  stageV(0);
  writeP(0);
  readPA();
  __syncthreads();          // V0 resident
  pvHalf();
  __syncthreads();          // done reading V0
  stageV(1);
  writeP(1);
  readPA();
  __syncthreads();          // V1 resident
  pvHalf();

  // ---- store O (f32, out[b][t][h][d])
  #pragma unroll
  for (int jt = 0; jt < 8; ++jt)
    #pragma unroll
    for (int r = 0; r < 4; ++r) {
      int q = n * 128 + qrow0 + g * 4 + r;
      out[(((size_t)b * 4096 + q) * 12 + h) * 128 + jt * 16 + li] = O[jt][r];
    }
}

// ---------------------------------------------------------------------------
extern "C" void kernel_launch(void* const* d_in, const int* in_sizes, int n_in,
                              void* d_out, int out_size, void* d_ws, size_t ws_size,
                              hipStream_t stream) {
  const float* x = (const float*)d_in[0];
  const float* Wq = (const float*)d_in[1];
  const float* Wk = (const float*)d_in[2];
  const float* Wv = (const float*)d_in[3];
  const float* Wpos = (const float*)d_in[4];
  const float* pds = (const float*)d_in[5];
  float* out = (float*)d_out;

  char* ws = (char*)d_ws;
  unsigned short* xb   = (unsigned short*)(ws);              // 16384*1536 bf16
  unsigned short* Wt   = (unsigned short*)(ws + 50331648);   // 6144*1536 bf16
  unsigned short* emb  = (unsigned short*)(ws + 69206016);   // 128*1536 bf16
  unsigned short* posb = (unsigned short*)(ws + 69599232);   // 12*128*128 bf16
  unsigned short* kbuf = (unsigned short*)(ws + 69992448);   // 4*12*4224*128 bf16
  unsigned short* vtb  = (unsigned short*)(ws + 121896960);  // 4*12*128*4352 bf16
  unsigned short* qbuf = (unsigned short*)(ws + 175374336);  // 4*12*4096*128 bf16
  float* posPart = (float*)ws;   // 3*128*1536 f32, reuses xb (dead post-GEMM)
  if (ws_size < 225705984) return;

  convert_x<<<2048, 256, 0, stream>>>((const float4*)x, (u16x4*)xb);
  wt_kernel<<<dim3(24, 24, 4), 256, 0, stream>>>(Wq, Wk, Wv, Wpos, pds, Wt);
  emb_kernel<<<128, 256, 0, stream>>>(emb);
  gemm256b_kernel<<<1152, 512, 0, stream>>>(xb, Wt, qbuf, kbuf, vtb);
  posgemm_kernel<<<36, 256, 0, stream>>>(emb, Wt + (size_t)4608 * 1536, posPart);
  posreduce_kernel<<<192, 256, 0, stream>>>(posPart, posb);
  attn_kernel<<<1536, 512, 0, stream>>>(qbuf, kbuf, vtb, posb, out);
}

// Round 10
// 481.615 us; speedup vs baseline: 3.4780x; 3.4780x over previous
//
#include <hip/hip_runtime.h>
#include <cstdint>

// ---------------------------------------------------------------------------
// Gemma4 audio local attention, MI355X/gfx950.
// Pipeline: x->bf16 | W^T(+scales)->bf16 | sinusoid emb | QKV GEMM (128x128,
// BK=32, 32KB LDS dbuf -> 4 blocks/CU co-residency, VGPR-audited) | pos GEMM
// (split-K x3) | fused local attention (8 waves, LDS-staged K/V).
// ---------------------------------------------------------------------------

typedef __attribute__((ext_vector_type(8))) short s16x8;   // 8 x bf16 (4 VGPR)
typedef __attribute__((ext_vector_type(4))) float f32x4;
typedef __attribute__((ext_vector_type(4))) unsigned short u16x4;

#define MFMA16(A, B, C) __builtin_amdgcn_mfma_f32_16x16x32_bf16(A, B, C, 0, 0, 0)

__device__ __forceinline__ unsigned short f2bf(float f) {
  unsigned u = __float_as_uint(f);
  u += 0x7FFFu + ((u >> 16) & 1u);          // RNE
  return (unsigned short)(u >> 16);
}
__device__ __forceinline__ float bf2f(unsigned short s) {
  return __uint_as_float(((unsigned)s) << 16);
}

// async global->LDS, 16B per lane. LDS dest is wave-uniform base + lane*16
// (linear in tid); global source is per-lane (pre-swizzled there).
__device__ __forceinline__ void gload16(const unsigned short* g, unsigned short* l) {
  __builtin_amdgcn_global_load_lds(
      (const __attribute__((address_space(1))) void*)(uintptr_t)g,
      (__attribute__((address_space(3))) void*)(unsigned)(uintptr_t)l,
      16, 0, 0);
}

// ---------------------------------------------------------------------------
// x f32 [16384][1536] -> bf16
__global__ void convert_x(const float4* __restrict__ x4, u16x4* __restrict__ o4) {
  int idx = blockIdx.x * 256 + threadIdx.x;
  #pragma unroll
  for (int i = 0; i < 12; ++i) {
    size_t k = (size_t)idx + (size_t)i * 524288;
    float4 v = x4[k];
    u16x4 o = {f2bf(v.x), f2bf(v.y), f2bf(v.z), f2bf(v.w)};
    o4[k] = o;
  }
}

// ---------------------------------------------------------------------------
// W^T with per-output-dim scales, bf16. Wt rows: [0,1536)=Wq^T*qscale,
// [1536,3072)=Wk^T*K_SCALE, [3072,4608)=Wv^T, [4608,6144)=Wpos^T.
__global__ void wt_kernel(const float* __restrict__ Wq, const float* __restrict__ Wk,
                          const float* __restrict__ Wv, const float* __restrict__ Wpos,
                          const float* __restrict__ pds, unsigned short* __restrict__ Wt) {
  int z = blockIdx.z;
  const float* W = (z == 0) ? Wq : (z == 1) ? Wk : (z == 2) ? Wv : Wpos;
  int k0 = blockIdx.x * 64, n0 = blockIdx.y * 64;
  __shared__ float tile[64][65];
  int tid = threadIdx.x;
  #pragma unroll
  for (int i = 0; i < 16; ++i) {
    int lin = i * 256 + tid, r = lin >> 6, c = lin & 63;
    tile[r][c] = W[(size_t)(k0 + r) * 1536 + n0 + c];
  }
  __syncthreads();
  const float LN2 = 0.6931471805599453f;
  #pragma unroll
  for (int i = 0; i < 16; ++i) {
    int lin = i * 256 + tid, r = lin >> 6, c = lin & 63;
    int nn = n0 + r;
    float scale = 1.f;
    if (z == 0) {
      float p = pds[nn & 127];
      float sp = (p > 20.f) ? p : log1pf(expf(p));
      scale = (0.08838834764831845f / LN2) * sp;   // Dh^-0.5/ln2 * softplus
    } else if (z == 1) {
      scale = 1.3132616875182228f / LN2;           // log1p(e)/ln2
    }
    Wt[(size_t)(z * 1536 + nn) * 1536 + k0 + c] = f2bf(tile[c][r] * scale);
  }
}

// ---------------------------------------------------------------------------
// sinusoidal embedding rows: emb[p][i], position = 127-p
__global__ void emb_kernel(unsigned short* __restrict__ emb) {
  int p = blockIdx.x, tid = threadIdx.x;
  float position = (float)(127 - p);
  float log_inc = logf(10000.f) / 767.f;
  #pragma unroll
  for (int j = 0; j < 6; ++j) {
    int i = tid + j * 256;
    int ii = (i < 768) ? i : i - 768;
    float arg = position * expf(-(float)ii * log_inc);
    float v = (i < 768) ? sinf(arg) : cosf(arg);
    emb[(size_t)p * 1536 + i] = f2bf(v);
  }
}

// ---------------------------------------------------------------------------
// 128x128x(K=1536) bf16 GEMM, BK=32, 32KB LDS dbuf -> 4 blocks/CU.
// Loop: stage(next) | 8x swizzled ds_read_b128 | 16 MFMA | barrier.
// Co-resident blocks fill barrier/staging stalls (m97/m114 mechanism).
// Tile 128x32 bf16, 4 chunks/row; swizzle slot = cs ^ ((r ^ r>>2) & 3):
// per-16-lane read phase each 4-bank span gets 2 lanes (free).
// Y = X@[Wq|Wk|Wv]^T -> q[b][h][t][d], k[b][h][127+t][d], v^T[b][h][d][127+t]
__global__ __launch_bounds__(256, 4) void gemmqkv_kernel(
    const unsigned short* __restrict__ A, const unsigned short* __restrict__ Bw,
    unsigned short* __restrict__ outq, unsigned short* __restrict__ outk,
    unsigned short* __restrict__ outv) {
  __shared__ __align__(16) unsigned short smem[2][8192];  // 32KB: [buf][A 4096|B 4096]
  const int tid = threadIdx.x;
  const int w = tid >> 6, l = tid & 63, g = l >> 4, li = l & 15;
  const int wr = w >> 1, wc = w & 1;

  // XCD-bijective swizzle (4608 % 8 == 0): XCD k owns tm-band [16k,16k+16).
  // Within band: 8tm x 6tn supertiles for L2 locality.
  int swz = (blockIdx.x & 7) * 576 + (blockIdx.x >> 3);
  int k = swz / 576, j = swz % 576;
  int st = j / 48, o = j % 48;
  const int tm = k * 16 + (st / 6) * 8 + o / 6;   // 0..127
  const int tn = (st % 6) * 6 + o % 6;            // 0..35

  const unsigned short* Ab = A + (size_t)tm * 128 * 1536;
  const unsigned short* Bb = Bw + (size_t)tn * 128 * 1536;

  f32x4 acc[4][4];
  #pragma unroll
  for (int i = 0; i < 4; ++i)
    #pragma unroll
    for (int jj = 0; jj < 4; ++jj) acc[i][jj] = f32x4{0.f, 0.f, 0.f, 0.f};

  // chunk c of a 128x32 tile: row = c>>2, slot = c&3; source pre-swizzled
  auto stage = [&](int buf, int kt) {
    int k0 = kt * 32;
    if (k0 >= 1536) k0 = 0;                  // tail prefetch: dead data, valid mem
    unsigned short* s = smem[buf];
    #pragma unroll
    for (int it = 0; it < 2; ++it) {
      int c = it * 256 + tid;
      int r = c >> 2, cs = c & 3;
      int sc = (cs ^ ((r ^ (r >> 2)) & 3)) << 3;
      gload16(Ab + (size_t)r * 1536 + k0 + sc, s + c * 8);
    }
    #pragma unroll
    for (int it = 0; it < 2; ++it) {
      int c = it * 256 + tid;
      int r = c >> 2, cs = c & 3;
      int sc = (cs ^ ((r ^ (r >> 2)) & 3)) << 3;
      gload16(Bb + (size_t)r * 1536 + k0 + sc, s + 4096 + c * 8);
    }
  };

  stage(0, 0);
  __syncthreads();
  for (int t = 0; t < 48; ++t) {
    if (t < 47) stage((t + 1) & 1, t + 1);   // issue next-tile loads FIRST
    const unsigned short* s = smem[t & 1];
    s16x8 af[4], bfm[4];
    #pragma unroll
    for (int mi = 0; mi < 4; ++mi) {
      int ar = wr * 64 + mi * 16 + li;
      int sl = g ^ ((ar ^ (ar >> 2)) & 3);
      af[mi] = *(const s16x8*)(s + ar * 32 + sl * 8);
    }
    #pragma unroll
    for (int ni = 0; ni < 4; ++ni) {
      int br = wc * 64 + ni * 16 + li;
      int sl = g ^ ((br ^ (br >> 2)) & 3);
      bfm[ni] = *(const s16x8*)(s + 4096 + br * 32 + sl * 8);
    }
    #pragma unroll
    for (int mi = 0; mi < 4; ++mi)
      #pragma unroll
      for (int ni = 0; ni < 4; ++ni)
        acc[mi][ni] = MFMA16(af[mi], bfm[ni], acc[mi][ni]);
    __syncthreads();                          // compiler drains vmcnt/lgkm here
  }

  // epilogue scatter: C/D layout col=lane&15, row=(lane>>4)*4+reg
  #pragma unroll
  for (int mi = 0; mi < 4; ++mi) {
    int mrow = tm * 128 + wr * 64 + mi * 16 + g * 4;
    int bb_ = mrow >> 12, tt = mrow & 4095;
    #pragma unroll
    for (int ni = 0; ni < 4; ++ni) {
      int ncol = tn * 128 + wc * 64 + ni * 16 + li;
      f32x4 v4 = acc[mi][ni];
      if (ncol < 1536) {
        int hh = ncol >> 7, dd = ncol & 127;
        #pragma unroll
        for (int r = 0; r < 4; ++r)
          outq[((size_t)(bb_ * 12 + hh) * 4096 + tt + r) * 128 + dd] = f2bf(v4[r]);
      } else if (ncol < 3072) {
        int nc = ncol - 1536, hh = nc >> 7, dd = nc & 127;
        #pragma unroll
        for (int r = 0; r < 4; ++r)
          outk[((size_t)(bb_ * 12 + hh) * 4224 + 127 + tt + r) * 128 + dd] = f2bf(v4[r]);
      } else {
        int nc = ncol - 3072, hh = nc >> 7, dd = nc & 127;
        size_t vo = ((size_t)(bb_ * 12 + hh) * 128 + dd) * 4352 + 127 + tt;
        #pragma unroll
        for (int r = 0; r < 4; ++r) outv[vo + r] = f2bf(v4[r]);
      }
    }
  }
}

// ---------------------------------------------------------------------------
// pos GEMM split-K: 128x(128x12)x512 per slice, 3 slices -> f32 partials.
// part[ks][p][col] f32; grid 36 = 12 tn x 3 ks.
__global__ __launch_bounds__(256, 2) void posgemm_kernel(
    const unsigned short* __restrict__ A, const unsigned short* __restrict__ Bw,
    float* __restrict__ part) {
  __shared__ __align__(16) unsigned short smem[2][16384];
  const int tid = threadIdx.x;
  const int w = tid >> 6, l = tid & 63, g = l >> 4, li = l & 15;
  const int wr = w >> 1, wc = w & 1;
  const int tn = blockIdx.x % 12, ks = blockIdx.x / 12;

  const unsigned short* Ab = A;
  const unsigned short* Bb = Bw + (size_t)tn * 128 * 1536;

  f32x4 acc[4][4];
  #pragma unroll
  for (int i = 0; i < 4; ++i)
    #pragma unroll
    for (int j = 0; j < 4; ++j) acc[i][j] = f32x4{0.f, 0.f, 0.f, 0.f};

  auto stage = [&](int buf, int kk) {
    unsigned short* s = smem[buf];
    #pragma unroll
    for (int it = 0; it < 4; ++it) {
      int chunk = it * 256 + tid;
      int r = chunk >> 3, cs = chunk & 7;
      gload16(Ab + (size_t)r * 1536 + kk * 64 + ((cs ^ (r & 7)) << 3), s + chunk * 8);
    }
    #pragma unroll
    for (int it = 0; it < 4; ++it) {
      int chunk = it * 256 + tid;
      int r = chunk >> 3, cs = chunk & 7;
      gload16(Bb + (size_t)r * 1536 + kk * 64 + ((cs ^ (r & 7)) << 3),
              s + 8192 + chunk * 8);
    }
  };

  stage(0, ks * 8);
  __syncthreads();
  for (int t = 0; t < 8; ++t) {
    if (t < 7) stage((t + 1) & 1, ks * 8 + t + 1);
    const unsigned short* s = smem[t & 1];
    #pragma unroll
    for (int kk = 0; kk < 2; ++kk) {
      s16x8 af[4], bfm[4];
      #pragma unroll
      for (int mi = 0; mi < 4; ++mi) {
        int ar = wr * 64 + mi * 16 + li;
        int ch = (kk * 4 + g) ^ (ar & 7);
        af[mi] = *(const s16x8*)(s + ar * 64 + ch * 8);
      }
      #pragma unroll
      for (int ni = 0; ni < 4; ++ni) {
        int br = wc * 64 + ni * 16 + li;
        int ch = (kk * 4 + g) ^ (br & 7);
        bfm[ni] = *(const s16x8*)(s + 8192 + br * 64 + ch * 8);
      }
      #pragma unroll
      for (int mi = 0; mi < 4; ++mi)
        #pragma unroll
        for (int ni = 0; ni < 4; ++ni)
          acc[mi][ni] = MFMA16(af[mi], bfm[ni], acc[mi][ni]);
    }
    __syncthreads();
  }

  #pragma unroll
  for (int mi = 0; mi < 4; ++mi) {
    int mrow = wr * 64 + mi * 16 + g * 4;
    #pragma unroll
    for (int ni = 0; ni < 4; ++ni) {
      int ncol = tn * 128 + wc * 64 + ni * 16 + li;
      f32x4 v4 = acc[mi][ni];
      #pragma unroll
      for (int r = 0; r < 4; ++r)
        part[((size_t)ks * 128 + mrow + r) * 1536 + ncol] = v4[r];
    }
  }
}

// reduce 3 f32 partials -> posb[h][p][d] bf16
__global__ void posreduce_kernel(const float* __restrict__ part,
                                 unsigned short* __restrict__ posb) {
  int e = (blockIdx.x * 256 + threadIdx.x) * 4;   // 196608 elems, grid 192
  float4 a = *(const float4*)(part + e);
  float4 b = *(const float4*)(part + 196608 + e);
  float4 c = *(const float4*)(part + 393216 + e);
  int p = e / 1536, col = e % 1536;
  u16x4 o = {f2bf(a.x + b.x + c.x), f2bf(a.y + b.y + c.y),
             f2bf(a.z + b.z + c.z), f2bf(a.w + b.w + c.w)};
  *(u16x4*)(posb + ((size_t)(col >> 7) * 128 + p) * 128 + (col & 127)) = o;
}

// ---------------------------------------------------------------------------
// Fused blocked local attention (R4 version, proven). 1 block = (b,h,n)
// 128-query tile, 8 waves x 16 q-rows. K/V staged cooperatively into a 32KB
// LDS buffer (time-shared K0,K1,V0,V1) via global_load_lds with XOR-swizzled
// source; QP then P live in a second 32KB region (wave-private rows).
__global__ __launch_bounds__(512, 4) void attn_kernel(
    const unsigned short* __restrict__ qb, const unsigned short* __restrict__ kb,
    const unsigned short* __restrict__ vt, const unsigned short* __restrict__ posb,
    float* __restrict__ out) {
  __shared__ __align__(16) unsigned short kv[16384];    // 32KB: K/V half-tiles
  __shared__ __align__(16) unsigned short pbuf[16384];  // 32KB: QP then P
  const int tid = threadIdx.x;
  const int w = tid >> 6, l = tid & 63, g = l >> 4, li = l & 15;
  int bid = blockIdx.x;
  bid = (bid & 7) * 192 + (bid >> 3);   // XCD swizzle: adjacent n share K/V
  const int n = bid & 31, h = (bid >> 5) % 12, b = bid / 384;
  const int qrow0 = w * 16;             // wave-local q base (block-local)

  auto stageK = [&](int half) {
    const unsigned short* kb0 =
        kb + ((size_t)(b * 12 + h) * 4224 + n * 128 + half * 128) * 128;
    #pragma unroll
    for (int it = 0; it < 4; ++it) {
      int chunk = it * 512 + tid;
      int row = chunk >> 4, sl = chunk & 15;
      gload16(kb0 + row * 128 + ((sl ^ ((row & 7) << 1)) << 3), kv + chunk * 8);
    }
  };
  auto stageV = [&](int half) {
    const unsigned short* vb0 =
        vt + (size_t)(b * 12 + h) * 128 * 4352 + n * 128 + half * 128;
    #pragma unroll
    for (int it = 0; it < 4; ++it) {
      int chunk = it * 512 + tid;
      int row = chunk >> 4, sl = chunk & 15;
      gload16(vb0 + (size_t)row * 4352 + ((sl ^ ((row & 7) << 1)) << 3),
              kv + chunk * 8);
    }
  };

  stageK(0);  // issue ASAP; QP compute below overlaps the loads

  // ---- Q fragments (A-frag: row=li, k = kt*32+g*8)
  s16x8 aq[4];
  const unsigned short* qbase =
      qb + ((size_t)(b * 12 + h) * 4096 + n * 128 + qrow0 + li) * 128 + g * 8;
  #pragma unroll
  for (int kt = 0; kt < 4; ++kt) aq[kt] = *(const s16x8*)(qbase + kt * 32);

  // ---- QP = Q * pos^T -> pbuf rows [qrow0, qrow0+16), linear [q][p]
  const unsigned short* pb = posb + (size_t)h * 128 * 128;
  #pragma unroll
  for (int pt = 0; pt < 8; ++pt) {
    f32x4 a = {0.f, 0.f, 0.f, 0.f};
    #pragma unroll
    for (int kt = 0; kt < 4; ++kt) {
      s16x8 bp = *(const s16x8*)(pb + (pt * 16 + li) * 128 + kt * 32 + g * 8);
      a = MFMA16(aq[kt], bp, a);
    }
    #pragma unroll
    for (int r = 0; r < 4; ++r)
      pbuf[(qrow0 + g * 4 + r) * 128 + pt * 16 + li] = f2bf(a[r]);
  }

  f32x4 S[16];

  auto sHalf = [&](int half) {
    #pragma unroll
    for (int c8 = 0; c8 < 8; ++c8) {
      int rowc = c8 * 16 + li;
      f32x4 s = {0.f, 0.f, 0.f, 0.f};
      #pragma unroll
      for (int kt = 0; kt < 4; ++kt) {
        int slot = (kt * 4 + g) ^ ((rowc & 7) << 1);
        s16x8 bk = *(const s16x8*)(kv + rowc * 128 + slot * 8);
        s = MFMA16(aq[kt], bk, s);
      }
      S[half * 8 + c8] = s;
    }
    #pragma unroll
    for (int c8 = 0; c8 < 8; ++c8) {
      int ct = half * 8 + c8;
      #pragma unroll
      for (int r = 0; r < 4; ++r) {
        int qq = qrow0 + g * 4 + r;       // block-local q
        int cc = ct * 16 + li;            // block-local ctx
        int p = cc - qq;
        bool win = ((unsigned)p < 128u);
        float bd = bf2f(pbuf[qq * 128 + (p & 127)]);
        float sv = S[ct][r] + (win ? bd : 0.f);
        float e2 = exp2f(sv * 0.0577078016355585f);   // (2/50)*log2(e)
        sv = 50.f - 100.f / (e2 + 1.f);               // 50*tanh(s/50), NaN-free
        bool vld = win && (n * 128 + cc >= 127);      // key t >= 0
        S[ct][r] = vld ? sv : -3e38f;
      }
    }
  };

  __syncthreads();          // K0 resident
  sHalf(0);
  __syncthreads();          // all waves done reading K0
  stageK(1);
  __syncthreads();          // K1 resident
  sHalf(1);

  // ---- softmax (full row in regs)
  float inv_[4];
  #pragma unroll
  for (int r = 0; r < 4; ++r) {
    float m_ = -3e38f;
    #pragma unroll
    for (int ct = 0; ct < 16; ++ct) m_ = fmaxf(m_, S[ct][r]);
    #pragma unroll
    for (int d = 1; d < 16; d <<= 1) m_ = fmaxf(m_, __shfl_xor(m_, d));
    float sum = 0.f;
    #pragma unroll
    for (int ct = 0; ct < 16; ++ct) {
      float e = exp2f((S[ct][r] - m_) * 1.4426950408889634f);
      S[ct][r] = e;
      sum += e;
    }
    #pragma unroll
    for (int d = 1; d < 16; d <<= 1) sum += __shfl_xor(sum, d);
    inv_[r] = 1.f / sum;
  }

  f32x4 O[8];
  #pragma unroll
  for (int jt = 0; jt < 8; ++jt) O[jt] = f32x4{0.f, 0.f, 0.f, 0.f};
  s16x8 pa[4];

  auto writeP = [&](int half) {
    #pragma unroll
    for (int c8 = 0; c8 < 8; ++c8)
      #pragma unroll
      for (int r = 0; r < 4; ++r) {
        int row = qrow0 + g * 4 + r;
        int slot = (c8 * 2 + (li >> 3)) ^ ((row & 7) << 1);
        pbuf[row * 128 + slot * 8 + (li & 7)] = f2bf(S[half * 8 + c8][r] * inv_[r]);
      }
  };
  auto readPA = [&]() {
    #pragma unroll
    for (int c = 0; c < 4; ++c) {
      int row = qrow0 + li;
      int slot = (c * 4 + g) ^ ((li & 7) << 1);
      pa[c] = *(const s16x8*)(pbuf + row * 128 + slot * 8);
    }
  };
  auto pvHalf = [&]() {
    #pragma unroll
    for (int jt = 0; jt < 8; ++jt) {
      int rowd = jt * 16 + li;
      #pragma unroll
      for (int c = 0; c < 4; ++c) {
        int slot = (c * 4 + g) ^ ((rowd & 7) << 1);
        s16x8 bv = *(const s16x8*)(kv + rowd * 128 + slot * 8);
        O[jt] = MFMA16(pa[c], bv, O[jt]);
      }
    }
  };

  __syncthreads();          // all waves done reading K1 (kv free for V0)
  stageV(0);
  writeP(0);
  readPA();
  __syncthreads();          // V0 resident
  pvHalf();
  __syncthreads();          // done reading V0
  stageV(1);
  writeP(1);
  readPA();
  __syncthreads();          // V1 resident
  pvHalf();

  // ---- store O (f32, out[b][t][h][d])
  #pragma unroll
  for (int jt = 0; jt < 8; ++jt)
    #pragma unroll
    for (int r = 0; r < 4; ++r) {
      int q = n * 128 + qrow0 + g * 4 + r;
      out[(((size_t)b * 4096 + q) * 12 + h) * 128 + jt * 16 + li] = O[jt][r];
    }
}

// ---------------------------------------------------------------------------
extern "C" void kernel_launch(void* const* d_in, const int* in_sizes, int n_in,
                              void* d_out, int out_size, void* d_ws, size_t ws_size,
                              hipStream_t stream) {
  const float* x = (const float*)d_in[0];
  const float* Wq = (const float*)d_in[1];
  const float* Wk = (const float*)d_in[2];
  const float* Wv = (const float*)d_in[3];
  const float* Wpos = (const float*)d_in[4];
  const float* pds = (const float*)d_in[5];
  float* out = (float*)d_out;

  char* ws = (char*)d_ws;
  unsigned short* xb   = (unsigned short*)(ws);              // 16384*1536 bf16
  unsigned short* Wt   = (unsigned short*)(ws + 50331648);   // 6144*1536 bf16
  unsigned short* emb  = (unsigned short*)(ws + 69206016);   // 128*1536 bf16
  unsigned short* posb = (unsigned short*)(ws + 69599232);   // 12*128*128 bf16
  unsigned short* kbuf = (unsigned short*)(ws + 69992448);   // 4*12*4224*128 bf16
  unsigned short* vtb  = (unsigned short*)(ws + 121896960);  // 4*12*128*4352 bf16
  unsigned short* qbuf = (unsigned short*)(ws + 175374336);  // 4*12*4096*128 bf16
  float* posPart = (float*)ws;   // 3*128*1536 f32, reuses xb (dead post-GEMM)
  if (ws_size < 225705984) return;

  convert_x<<<2048, 256, 0, stream>>>((const float4*)x, (u16x4*)xb);
  wt_kernel<<<dim3(24, 24, 4), 256, 0, stream>>>(Wq, Wk, Wv, Wpos, pds, Wt);
  emb_kernel<<<128, 256, 0, stream>>>(emb);
  gemmqkv_kernel<<<4608, 256, 0, stream>>>(xb, Wt, qbuf, kbuf, vtb);
  posgemm_kernel<<<36, 256, 0, stream>>>(emb, Wt + (size_t)4608 * 1536, posPart);
  posreduce_kernel<<<192, 256, 0, stream>>>(posPart, posb);
  attn_kernel<<<1536, 512, 0, stream>>>(qbuf, kbuf, vtb, posb, out);
}

// Round 11
// 459.450 us; speedup vs baseline: 3.6458x; 1.0482x over previous
//
#include <hip/hip_runtime.h>
#include <cstdint>

// ---------------------------------------------------------------------------
// Gemma4 audio local attention, MI355X/gfx950.
// Pipeline: x->bf16 | W^T(+scales)->bf16 | sinusoid emb | QKV GEMM (256x256
// one-barrier 8-phase pipeline, R4 schedule — best measured 270us) | pos GEMM
// (split-K x3 + reduce) | fused local attention (8 waves, LDS-staged K/V).
// ---------------------------------------------------------------------------

typedef __attribute__((ext_vector_type(8))) short s16x8;   // 8 x bf16 (4 VGPR)
typedef __attribute__((ext_vector_type(4))) float f32x4;
typedef __attribute__((ext_vector_type(4))) unsigned short u16x4;

#define MFMA16(A, B, C) __builtin_amdgcn_mfma_f32_16x16x32_bf16(A, B, C, 0, 0, 0)

__device__ __forceinline__ unsigned short f2bf(float f) {
  unsigned u = __float_as_uint(f);
  u += 0x7FFFu + ((u >> 16) & 1u);          // RNE
  return (unsigned short)(u >> 16);
}
__device__ __forceinline__ float bf2f(unsigned short s) {
  return __uint_as_float(((unsigned)s) << 16);
}

// async global->LDS, 16B per lane. LDS dest is wave-uniform base + lane*16
// (linear in tid); global source is per-lane (pre-swizzled there).
__device__ __forceinline__ void gload16(const unsigned short* g, unsigned short* l) {
  __builtin_amdgcn_global_load_lds(
      (const __attribute__((address_space(1))) void*)(uintptr_t)g,
      (__attribute__((address_space(3))) void*)(unsigned)(uintptr_t)l,
      16, 0, 0);
}

// ---------------------------------------------------------------------------
// x f32 [16384][1536] -> bf16
__global__ void convert_x(const float4* __restrict__ x4, u16x4* __restrict__ o4) {
  int idx = blockIdx.x * 256 + threadIdx.x;
  #pragma unroll
  for (int i = 0; i < 12; ++i) {
    size_t k = (size_t)idx + (size_t)i * 524288;
    float4 v = x4[k];
    u16x4 o = {f2bf(v.x), f2bf(v.y), f2bf(v.z), f2bf(v.w)};
    o4[k] = o;
  }
}

// ---------------------------------------------------------------------------
// W^T with per-output-dim scales, bf16. Wt rows: [0,1536)=Wq^T*qscale,
// [1536,3072)=Wk^T*K_SCALE, [3072,4608)=Wv^T, [4608,6144)=Wpos^T.
__global__ void wt_kernel(const float* __restrict__ Wq, const float* __restrict__ Wk,
                          const float* __restrict__ Wv, const float* __restrict__ Wpos,
                          const float* __restrict__ pds, unsigned short* __restrict__ Wt) {
  int z = blockIdx.z;
  const float* W = (z == 0) ? Wq : (z == 1) ? Wk : (z == 2) ? Wv : Wpos;
  int k0 = blockIdx.x * 64, n0 = blockIdx.y * 64;
  __shared__ float tile[64][65];
  int tid = threadIdx.x;
  #pragma unroll
  for (int i = 0; i < 16; ++i) {
    int lin = i * 256 + tid, r = lin >> 6, c = lin & 63;
    tile[r][c] = W[(size_t)(k0 + r) * 1536 + n0 + c];
  }
  __syncthreads();
  const float LN2 = 0.6931471805599453f;
  #pragma unroll
  for (int i = 0; i < 16; ++i) {
    int lin = i * 256 + tid, r = lin >> 6, c = lin & 63;
    int nn = n0 + r;
    float scale = 1.f;
    if (z == 0) {
      float p = pds[nn & 127];
      float sp = (p > 20.f) ? p : log1pf(expf(p));
      scale = (0.08838834764831845f / LN2) * sp;   // Dh^-0.5/ln2 * softplus
    } else if (z == 1) {
      scale = 1.3132616875182228f / LN2;           // log1p(e)/ln2
    }
    Wt[(size_t)(z * 1536 + nn) * 1536 + k0 + c] = f2bf(tile[c][r] * scale);
  }
}

// ---------------------------------------------------------------------------
// sinusoidal embedding rows: emb[p][i], position = 127-p
__global__ void emb_kernel(unsigned short* __restrict__ emb) {
  int p = blockIdx.x, tid = threadIdx.x;
  float position = (float)(127 - p);
  float log_inc = logf(10000.f) / 767.f;
  #pragma unroll
  for (int j = 0; j < 6; ++j) {
    int i = tid + j * 256;
    int ii = (i < 768) ? i : i - 768;
    float arg = position * expf(-(float)ii * log_inc);
    float v = (i < 768) ? sinf(arg) : cosf(arg);
    emb[(size_t)p * 1536 + i] = f2bf(v);
  }
}

// ---------------------------------------------------------------------------
// st_16x32-swizzled LDS tile accessor. Tile = 256x64 bf16 stored as
// [row>>4][col>>5] subtiles of 1024B; within subtile byte ^= ((byte>>9)&1)<<5.
__device__ __forceinline__ const s16x8* ldsFrag(const unsigned short* tile,
                                                int row, int col) {
  int byte = ((((row >> 4) << 1) + (col >> 5)) << 10) +
             (((((row & 15) << 6) | ((col & 31) << 1))) ^ ((row & 8) << 2));
  return (const s16x8*)((const char*)tile + byte);
}

// One pipelined phase (R4): stage 1 half-tile, prefetch NEXT phase's
// fragments, MFMA THIS phase (regs loaded last phase), lgkm-drain, counted
// vmcnt at the two checkpoints, single barrier pair.
template <int P, typename F>
__device__ __forceinline__ void phase8(const unsigned short* lds, int wm, int wn,
                                       int li, int g, s16x8 (&af)[2][4],
                                       s16x8 (&bf)[2][4], f32x4 (&acc)[8][4],
                                       F&& stage) {
  constexpr int MH = P & 1, KS = (P >> 1) & 1;
  constexpr int PN = (P + 1) & 7;
  constexpr int NBUF = (PN < 4) ? 0 : 1, NMH = PN & 1, NKS = (PN >> 1) & 1;
  stage();                                   // global_load_lds (vmcnt +2)
  const unsigned short* At = lds + NBUF * 32768;
  #pragma unroll
  for (int fi = 0; fi < 4; ++fi)
    af[PN & 1][fi] = *ldsFrag(At, wm * 128 + NMH * 64 + fi * 16 + li,
                              NKS * 32 + g * 8);
  if constexpr (NMH == 0) {
    const unsigned short* Bt = lds + NBUF * 32768 + 16384;
    #pragma unroll
    for (int fj = 0; fj < 4; ++fj)
      bf[NKS][fj] = *ldsFrag(Bt, wn * 64 + fj * 16 + li, NKS * 32 + g * 8);
  }
  __builtin_amdgcn_sched_barrier(0);         // loads issued before MFMA
  __builtin_amdgcn_s_setprio(1);
  #pragma unroll
  for (int fi = 0; fi < 4; ++fi)
    #pragma unroll
    for (int fj = 0; fj < 4; ++fj)
      acc[MH * 4 + fi][fj] = MFMA16(af[P & 1][fi], bf[KS][fj],
                                    acc[MH * 4 + fi][fj]);
  __builtin_amdgcn_s_setprio(0);
  asm volatile("s_waitcnt lgkmcnt(0)" ::: "memory");  // next-phase reads done
  if constexpr (P == 2 || P == 6)
    asm volatile("s_waitcnt vmcnt(2)" ::: "memory");  // counted, never 0
  __builtin_amdgcn_sched_barrier(0);
  __builtin_amdgcn_s_barrier();
  __builtin_amdgcn_sched_barrier(0);
}

// ---------------------------------------------------------------------------
// 256x256x(K=1536) bf16 GEMM, one-barrier 8-phase pipeline (R4 schedule,
// best measured: 269.8us, MfmaUtil 37%, conflicts 0).
// Y = X@[Wq|Wk|Wv]^T -> q[b][h][t][d], k[b][h][127+t][d], v^T[b][h][d][127+t]
__global__ __launch_bounds__(512, 2) void gemm256_kernel(
    const unsigned short* __restrict__ A, const unsigned short* __restrict__ Bw,
    unsigned short* __restrict__ outq, unsigned short* __restrict__ outk,
    unsigned short* __restrict__ outv) {
  __shared__ __align__(16) unsigned short lds[65536];  // 128KB: 2x(A 32K + B 32K)
  unsigned short* ldsw = lds;
  const int tid = threadIdx.x;
  const int w = tid >> 6, l = tid & 63, g = l >> 4, li = l & 15;
  const int wm = w >> 2, wn = w & 3;

  // XCD-bijective swizzle (1152 % 8 == 0) + 8x6 supertiles for L2 locality
  int swz = (blockIdx.x & 7) * 144 + (blockIdx.x >> 3);
  int grp = swz / 48, idx = swz % 48;
  const int tm = (grp / 3) * 8 + idx / 6;    // 0..63
  const int tn = (grp % 3) * 6 + idx % 6;    // 0..17

  const unsigned short* Ab = A + (size_t)tm * 256 * 1536;
  const unsigned short* Bb = Bw + (size_t)tn * 256 * 1536;

  // per-thread staging swizzle (inverse st_16x32 on the global source)
  int sr0, sc0, sr1, sc1;
  {
    int q = tid, off = (q & 63) << 4;
    off ^= ((off >> 9) & 1) << 5;
    sr0 = ((q >> 6) >> 1) * 16 + (off >> 6);
    sc0 = (((q >> 6) & 1) << 5) + ((off & 63) >> 1);
    q = 512 + tid; off = (q & 63) << 4;
    off ^= ((off >> 9) & 1) << 5;
    sr1 = ((q >> 6) >> 1) * 16 + (off >> 6);
    sc1 = (((q >> 6) & 1) << 5) + ((off & 63) >> 1);
  }
  auto stage = [&](int dstE, const unsigned short* src, int row0, int kt) {
    int k0 = kt * 64;
    if (k0 >= 1536) k0 -= 1536;               // tail prefetch wraps (L2-hot, dead)
    gload16(src + (size_t)(row0 + sr0) * 1536 + k0 + sc0, ldsw + dstE + tid * 8);
    gload16(src + (size_t)(row0 + sr1) * 1536 + k0 + sc1,
            ldsw + dstE + 4096 + tid * 8);
  };

  f32x4 acc[8][4];
  #pragma unroll
  for (int i = 0; i < 8; ++i)
    #pragma unroll
    for (int j = 0; j < 4; ++j) acc[i][j] = f32x4{0.f, 0.f, 0.f, 0.f};
  s16x8 af[2][4], bf[2][4];

  // prologue: buf0 full (k-tile 0) + buf1.B (k-tile 1); preload p0 frags
  stage(0,     Ab, 0,   0);
  stage(8192,  Ab, 128, 0);
  stage(16384, Bb, 0,   0);
  stage(24576, Bb, 128, 0);
  stage(49152, Bb, 0,   1);
  stage(57344, Bb, 128, 1);
  asm volatile("s_waitcnt vmcnt(4)" ::: "memory");   // buf0 resident
  __builtin_amdgcn_s_barrier();
  __builtin_amdgcn_sched_barrier(0);
  #pragma unroll
  for (int fi = 0; fi < 4; ++fi)
    af[0][fi] = *ldsFrag(lds, wm * 128 + fi * 16 + li, g * 8);
  #pragma unroll
  for (int fj = 0; fj < 4; ++fj)
    bf[0][fj] = *ldsFrag(lds + 16384, wn * 64 + fj * 16 + li, g * 8);

  for (int t = 0; t < 12; ++t) {
    const int b1 = 2 * t + 1, b2 = 2 * t + 2, b3 = 2 * t + 3;
    phase8<0>(lds, wm, wn, li, g, af, bf, acc, [&]{ stage(32768, Ab, 0,   b1); });
    phase8<1>(lds, wm, wn, li, g, af, bf, acc, [&]{ stage(40960, Ab, 128, b1); });
    phase8<2>(lds, wm, wn, li, g, af, bf, acc, [&]{ stage(16384, Bb, 0,   b2); });
    phase8<3>(lds, wm, wn, li, g, af, bf, acc, [&]{ stage(24576, Bb, 128, b2); });
    phase8<4>(lds, wm, wn, li, g, af, bf, acc, [&]{ stage(0,     Ab, 0,   b2); });
    phase8<5>(lds, wm, wn, li, g, af, bf, acc, [&]{ stage(8192,  Ab, 128, b2); });
    phase8<6>(lds, wm, wn, li, g, af, bf, acc, [&]{ stage(49152, Bb, 0,   b3); });
    phase8<7>(lds, wm, wn, li, g, af, bf, acc, [&]{ stage(57344, Bb, 128, b3); });
  }

  // epilogue scatter: C/D layout col=lane&15, row=(lane>>4)*4+reg
  #pragma unroll
  for (int mf = 0; mf < 8; ++mf) {
    int mrow = tm * 256 + wm * 128 + mf * 16 + g * 4;
    int bb_ = mrow >> 12, tt = mrow & 4095;
    #pragma unroll
    for (int fj = 0; fj < 4; ++fj) {
      int ncol = tn * 256 + wn * 64 + fj * 16 + li;
      f32x4 v4 = acc[mf][fj];
      if (ncol < 1536) {
        int hh = ncol >> 7, dd = ncol & 127;
        #pragma unroll
        for (int r = 0; r < 4; ++r)
          outq[((size_t)(bb_ * 12 + hh) * 4096 + tt + r) * 128 + dd] = f2bf(v4[r]);
      } else if (ncol < 3072) {
        int nc = ncol - 1536, hh = nc >> 7, dd = nc & 127;
        #pragma unroll
        for (int r = 0; r < 4; ++r)
          outk[((size_t)(bb_ * 12 + hh) * 4224 + 127 + tt + r) * 128 + dd] = f2bf(v4[r]);
      } else {
        int nc = ncol - 3072, hh = nc >> 7, dd = nc & 127;
        size_t vo = ((size_t)(bb_ * 12 + hh) * 128 + dd) * 4352 + 127 + tt;
        #pragma unroll
        for (int r = 0; r < 4; ++r) outv[vo + r] = f2bf(v4[r]);
      }
    }
  }
}

// ---------------------------------------------------------------------------
// pos GEMM split-K: 128x(128x12)x512 per slice, 3 slices -> f32 partials.
// part[ks][p][col] f32; grid 36 = 12 tn x 3 ks.
__global__ __launch_bounds__(256, 2) void posgemm_kernel(
    const unsigned short* __restrict__ A, const unsigned short* __restrict__ Bw,
    float* __restrict__ part) {
  __shared__ __align__(16) unsigned short smem[2][16384];
  const int tid = threadIdx.x;
  const int w = tid >> 6, l = tid & 63, g = l >> 4, li = l & 15;
  const int wr = w >> 1, wc = w & 1;
  const int tn = blockIdx.x % 12, ks = blockIdx.x / 12;

  const unsigned short* Ab = A;
  const unsigned short* Bb = Bw + (size_t)tn * 128 * 1536;

  f32x4 acc[4][4];
  #pragma unroll
  for (int i = 0; i < 4; ++i)
    #pragma unroll
    for (int j = 0; j < 4; ++j) acc[i][j] = f32x4{0.f, 0.f, 0.f, 0.f};

  auto stage = [&](int buf, int kk) {
    unsigned short* s = smem[buf];
    #pragma unroll
    for (int it = 0; it < 4; ++it) {
      int chunk = it * 256 + tid;
      int r = chunk >> 3, cs = chunk & 7;
      gload16(Ab + (size_t)r * 1536 + kk * 64 + ((cs ^ (r & 7)) << 3), s + chunk * 8);
    }
    #pragma unroll
    for (int it = 0; it < 4; ++it) {
      int chunk = it * 256 + tid;
      int r = chunk >> 3, cs = chunk & 7;
      gload16(Bb + (size_t)r * 1536 + kk * 64 + ((cs ^ (r & 7)) << 3),
              s + 8192 + chunk * 8);
    }
  };

  stage(0, ks * 8);
  __syncthreads();
  for (int t = 0; t < 8; ++t) {
    if (t < 7) stage((t + 1) & 1, ks * 8 + t + 1);
    const unsigned short* s = smem[t & 1];
    #pragma unroll
    for (int kk = 0; kk < 2; ++kk) {
      s16x8 af[4], bfm[4];
      #pragma unroll
      for (int mi = 0; mi < 4; ++mi) {
        int ar = wr * 64 + mi * 16 + li;
        int ch = (kk * 4 + g) ^ (ar & 7);
        af[mi] = *(const s16x8*)(s + ar * 64 + ch * 8);
      }
      #pragma unroll
      for (int ni = 0; ni < 4; ++ni) {
        int br = wc * 64 + ni * 16 + li;
        int ch = (kk * 4 + g) ^ (br & 7);
        bfm[ni] = *(const s16x8*)(s + 8192 + br * 64 + ch * 8);
      }
      #pragma unroll
      for (int mi = 0; mi < 4; ++mi)
        #pragma unroll
        for (int ni = 0; ni < 4; ++ni)
          acc[mi][ni] = MFMA16(af[mi], bfm[ni], acc[mi][ni]);
    }
    __syncthreads();
  }

  #pragma unroll
  for (int mi = 0; mi < 4; ++mi) {
    int mrow = wr * 64 + mi * 16 + g * 4;
    #pragma unroll
    for (int ni = 0; ni < 4; ++ni) {
      int ncol = tn * 128 + wc * 64 + ni * 16 + li;
      f32x4 v4 = acc[mi][ni];
      #pragma unroll
      for (int r = 0; r < 4; ++r)
        part[((size_t)ks * 128 + mrow + r) * 1536 + ncol] = v4[r];
    }
  }
}

// reduce 3 f32 partials -> posb[h][p][d] bf16
__global__ void posreduce_kernel(const float* __restrict__ part,
                                 unsigned short* __restrict__ posb) {
  int e = (blockIdx.x * 256 + threadIdx.x) * 4;   // 196608 elems, grid 192
  float4 a = *(const float4*)(part + e);
  float4 b = *(const float4*)(part + 196608 + e);
  float4 c = *(const float4*)(part + 393216 + e);
  int p = e / 1536, col = e % 1536;
  u16x4 o = {f2bf(a.x + b.x + c.x), f2bf(a.y + b.y + c.y),
             f2bf(a.z + b.z + c.z), f2bf(a.w + b.w + c.w)};
  *(u16x4*)(posb + ((size_t)(col >> 7) * 128 + p) * 128 + (col & 127)) = o;
}

// ---------------------------------------------------------------------------
// Fused blocked local attention (R4 version, proven). 1 block = (b,h,n)
// 128-query tile, 8 waves x 16 q-rows. K/V staged cooperatively into a 32KB
// LDS buffer (time-shared K0,K1,V0,V1) via global_load_lds with XOR-swizzled
// source; QP then P live in a second 32KB region (wave-private rows).
__global__ __launch_bounds__(512, 4) void attn_kernel(
    const unsigned short* __restrict__ qb, const unsigned short* __restrict__ kb,
    const unsigned short* __restrict__ vt, const unsigned short* __restrict__ posb,
    float* __restrict__ out) {
  __shared__ __align__(16) unsigned short kv[16384];    // 32KB: K/V half-tiles
  __shared__ __align__(16) unsigned short pbuf[16384];  // 32KB: QP then P
  const int tid = threadIdx.x;
  const int w = tid >> 6, l = tid & 63, g = l >> 4, li = l & 15;
  int bid = blockIdx.x;
  bid = (bid & 7) * 192 + (bid >> 3);   // XCD swizzle: adjacent n share K/V
  const int n = bid & 31, h = (bid >> 5) % 12, b = bid / 384;
  const int qrow0 = w * 16;             // wave-local q base (block-local)

  auto stageK = [&](int half) {
    const unsigned short* kb0 =
        kb + ((size_t)(b * 12 + h) * 4224 + n * 128 + half * 128) * 128;
    #pragma unroll
    for (int it = 0; it < 4; ++it) {
      int chunk = it * 512 + tid;
      int row = chunk >> 4, sl = chunk & 15;
      gload16(kb0 + row * 128 + ((sl ^ ((row & 7) << 1)) << 3), kv + chunk * 8);
    }
  };
  auto stageV = [&](int half) {
    const unsigned short* vb0 =
        vt + (size_t)(b * 12 + h) * 128 * 4352 + n * 128 + half * 128;
    #pragma unroll
    for (int it = 0; it < 4; ++it) {
      int chunk = it * 512 + tid;
      int row = chunk >> 4, sl = chunk & 15;
      gload16(vb0 + (size_t)row * 4352 + ((sl ^ ((row & 7) << 1)) << 3),
              kv + chunk * 8);
    }
  };

  stageK(0);  // issue ASAP; QP compute below overlaps the loads

  // ---- Q fragments (A-frag: row=li, k = kt*32+g*8)
  s16x8 aq[4];
  const unsigned short* qbase =
      qb + ((size_t)(b * 12 + h) * 4096 + n * 128 + qrow0 + li) * 128 + g * 8;
  #pragma unroll
  for (int kt = 0; kt < 4; ++kt) aq[kt] = *(const s16x8*)(qbase + kt * 32);

  // ---- QP = Q * pos^T -> pbuf rows [qrow0, qrow0+16), linear [q][p]
  const unsigned short* pb = posb + (size_t)h * 128 * 128;
  #pragma unroll
  for (int pt = 0; pt < 8; ++pt) {
    f32x4 a = {0.f, 0.f, 0.f, 0.f};
    #pragma unroll
    for (int kt = 0; kt < 4; ++kt) {
      s16x8 bp = *(const s16x8*)(pb + (pt * 16 + li) * 128 + kt * 32 + g * 8);
      a = MFMA16(aq[kt], bp, a);
    }
    #pragma unroll
    for (int r = 0; r < 4; ++r)
      pbuf[(qrow0 + g * 4 + r) * 128 + pt * 16 + li] = f2bf(a[r]);
  }

  f32x4 S[16];

  auto sHalf = [&](int half) {
    #pragma unroll
    for (int c8 = 0; c8 < 8; ++c8) {
      int rowc = c8 * 16 + li;
      f32x4 s = {0.f, 0.f, 0.f, 0.f};
      #pragma unroll
      for (int kt = 0; kt < 4; ++kt) {
        int slot = (kt * 4 + g) ^ ((rowc & 7) << 1);
        s16x8 bk = *(const s16x8*)(kv + rowc * 128 + slot * 8);
        s = MFMA16(aq[kt], bk, s);
      }
      S[half * 8 + c8] = s;
    }
    #pragma unroll
    for (int c8 = 0; c8 < 8; ++c8) {
      int ct = half * 8 + c8;
      #pragma unroll
      for (int r = 0; r < 4; ++r) {
        int qq = qrow0 + g * 4 + r;       // block-local q
        int cc = ct * 16 + li;            // block-local ctx
        int p = cc - qq;
        bool win = ((unsigned)p < 128u);
        float bd = bf2f(pbuf[qq * 128 + (p & 127)]);
        float sv = S[ct][r] + (win ? bd : 0.f);
        float e2 = exp2f(sv * 0.0577078016355585f);   // (2/50)*log2(e)
        sv = 50.f - 100.f / (e2 + 1.f);               // 50*tanh(s/50), NaN-free
        bool vld = win && (n * 128 + cc >= 127);      // key t >= 0
        S[ct][r] = vld ? sv : -3e38f;
      }
    }
  };

  __syncthreads();          // K0 resident
  sHalf(0);
  __syncthreads();          // all waves done reading K0
  stageK(1);
  __syncthreads();          // K1 resident
  sHalf(1);

  // ---- softmax (full row in regs)
  float inv_[4];
  #pragma unroll
  for (int r = 0; r < 4; ++r) {
    float m_ = -3e38f;
    #pragma unroll
    for (int ct = 0; ct < 16; ++ct) m_ = fmaxf(m_, S[ct][r]);
    #pragma unroll
    for (int d = 1; d < 16; d <<= 1) m_ = fmaxf(m_, __shfl_xor(m_, d));
    float sum = 0.f;
    #pragma unroll
    for (int ct = 0; ct < 16; ++ct) {
      float e = exp2f((S[ct][r] - m_) * 1.4426950408889634f);
      S[ct][r] = e;
      sum += e;
    }
    #pragma unroll
    for (int d = 1; d < 16; d <<= 1) sum += __shfl_xor(sum, d);
    inv_[r] = 1.f / sum;
  }

  f32x4 O[8];
  #pragma unroll
  for (int jt = 0; jt < 8; ++jt) O[jt] = f32x4{0.f, 0.f, 0.f, 0.f};
  s16x8 pa[4];

  auto writeP = [&](int half) {
    #pragma unroll
    for (int c8 = 0; c8 < 8; ++c8)
      #pragma unroll
      for (int r = 0; r < 4; ++r) {
        int row = qrow0 + g * 4 + r;
        int slot = (c8 * 2 + (li >> 3)) ^ ((row & 7) << 1);
        pbuf[row * 128 + slot * 8 + (li & 7)] = f2bf(S[half * 8 + c8][r] * inv_[r]);
      }
  };
  auto readPA = [&]() {
    #pragma unroll
    for (int c = 0; c < 4; ++c) {
      int row = qrow0 + li;
      int slot = (c * 4 + g) ^ ((li & 7) << 1);
      pa[c] = *(const s16x8*)(pbuf + row * 128 + slot * 8);
    }
  };
  auto pvHalf = [&]() {
    #pragma unroll
    for (int jt = 0; jt < 8; ++jt) {
      int rowd = jt * 16 + li;
      #pragma unroll
      for (int c = 0; c < 4; ++c) {
        int slot = (c * 4 + g) ^ ((rowd & 7) << 1);
        s16x8 bv = *(const s16x8*)(kv + rowd * 128 + slot * 8);
        O[jt] = MFMA16(pa[c], bv, O[jt]);
      }
    }
  };

  __syncthreads();          // all waves done reading K1 (kv free for V0)
  stageV(0);
  writeP(0);
  readPA();
  __syncthreads();          // V0 resident
  pvHalf();
  __syncthreads();          // done reading V0
  stageV(1);
  writeP(1);
  readPA();
  __syncthreads();          // V1 resident
  pvHalf();

  // ---- store O (f32, out[b][t][h][d])
  #pragma unroll
  for (int jt = 0; jt < 8; ++jt)
    #pragma unroll
    for (int r = 0; r < 4; ++r) {
      int q = n * 128 + qrow0 + g * 4 + r;
      out[(((size_t)b * 4096 + q) * 12 + h) * 128 + jt * 16 + li] = O[jt][r];
    }
}

// ---------------------------------------------------------------------------
extern "C" void kernel_launch(void* const* d_in, const int* in_sizes, int n_in,
                              void* d_out, int out_size, void* d_ws, size_t ws_size,
                              hipStream_t stream) {
  const float* x = (const float*)d_in[0];
  const float* Wq = (const float*)d_in[1];
  const float* Wk = (const float*)d_in[2];
  const float* Wv = (const float*)d_in[3];
  const float* Wpos = (const float*)d_in[4];
  const float* pds = (const float*)d_in[5];
  float* out = (float*)d_out;

  char* ws = (char*)d_ws;
  unsigned short* xb   = (unsigned short*)(ws);              // 16384*1536 bf16
  unsigned short* Wt   = (unsigned short*)(ws + 50331648);   // 6144*1536 bf16
  unsigned short* emb  = (unsigned short*)(ws + 69206016);   // 128*1536 bf16
  unsigned short* posb = (unsigned short*)(ws + 69599232);   // 12*128*128 bf16
  unsigned short* kbuf = (unsigned short*)(ws + 69992448);   // 4*12*4224*128 bf16
  unsigned short* vtb  = (unsigned short*)(ws + 121896960);  // 4*12*128*4352 bf16
  unsigned short* qbuf = (unsigned short*)(ws + 175374336);  // 4*12*4096*128 bf16
  float* posPart = (float*)ws;   // 3*128*1536 f32, reuses xb (dead post-GEMM)
  if (ws_size < 225705984) return;

  convert_x<<<2048, 256, 0, stream>>>((const float4*)x, (u16x4*)xb);
  wt_kernel<<<dim3(24, 24, 4), 256, 0, stream>>>(Wq, Wk, Wv, Wpos, pds, Wt);
  emb_kernel<<<128, 256, 0, stream>>>(emb);
  gemm256_kernel<<<1152, 512, 0, stream>>>(xb, Wt, qbuf, kbuf, vtb);
  posgemm_kernel<<<36, 256, 0, stream>>>(emb, Wt + (size_t)4608 * 1536, posPart);
  posreduce_kernel<<<192, 256, 0, stream>>>(posPart, posb);
  attn_kernel<<<1536, 512, 0, stream>>>(qbuf, kbuf, vtb, posb, out);
}